// Round 6
// baseline (633.246 us; speedup 1.0000x reference)
//
#include <hip/hip_runtime.h>

#define NROW 524288
#define KDIM 66
#define NSEG 65
#define NB   2048
#define PART_STRIDE 12

// ws layout: [0, NB*12*8): double partials; [NB*12*8, +4): u32 completion counter
#define CNT_OFF (NB * PART_STRIDE * 8)

// ---------------------------------------------------------------------------
// Compile-time precomputation of everything input-independent (round-4 fix:
// runtime version spilled ~5.3 KB/thread to scratch, 93.7 us).
// ---------------------------------------------------------------------------
struct Pre {
    float  xk[KDIM];
    float  dxf[NSEG];
    double av[KDIM];      // A^T lower diag
    double winv[KDIM];    // 1 / pivot
    double cp[KDIM];      // Thomas upper coeff
    double dxinv[NSEG];   // 1 / dx  (f64)
    double d3[NSEG];      // 3 * dx  (f64)
    double pp, qq, r1, r2;
};

constexpr Pre make_pre() {
    Pre p{};
    for (int k = 0; k < KDIM; ++k) p.xk[k] = (float)((1.0 / 65.0) * (double)k);
    p.xk[KDIM - 1] = 1.0f;
    for (int k = 0; k < NSEG; ++k) p.dxf[k] = p.xk[k + 1] - p.xk[k];

    double d02 = (double)(p.xk[2] - p.xk[0]);
    double dl  = (double)(p.xk[KDIM - 1] - p.xk[KDIM - 3]);

    double bv[KDIM] = {};
    double cv[KDIM] = {};
    bv[0] = (double)p.dxf[1];
    bv[KDIM - 1] = (double)p.dxf[KDIM - 3];
    for (int i = 1; i < KDIM - 1; ++i)
        bv[i] = 2.0 * ((double)p.dxf[i] + (double)p.dxf[i - 1]);
    p.av[0] = 0.0;
    p.av[1] = d02;
    for (int i = 2; i < KDIM; ++i) p.av[i] = (double)p.dxf[i - 2];
    for (int i = 0; i < KDIM - 2; ++i) cv[i] = (double)p.dxf[i + 1];
    cv[KDIM - 2] = dl;
    cv[KDIM - 1] = 0.0;

    double w = bv[0];
    p.winv[0] = 1.0 / w;
    p.cp[0]   = cv[0] / w;
    for (int i = 1; i < KDIM; ++i) {
        w = bv[i] - p.av[i] * p.cp[i - 1];
        p.winv[i] = 1.0 / w;
        p.cp[i]   = cv[i] / w;
    }
    for (int m = 0; m < NSEG; ++m) {
        p.dxinv[m] = 1.0 / (double)p.dxf[m];
        p.d3[m]    = 3.0 * (double)p.dxf[m];
    }
    p.pp = ((double)p.dxf[0] + 2.0 * d02) * (double)p.dxf[1] / d02;
    p.qq = (double)p.dxf[0] * (double)p.dxf[0] / d02;
    p.r1 = (double)p.dxf[64] * (double)p.dxf[64] / dl;
    p.r2 = (2.0 * dl + (double)p.dxf[64]) * (double)p.dxf[63] / dl;
    return p;
}

__device__ constexpr Pre PRE = make_pre();

// ---------------------------------------------------------------------------
// Single fused kernel:
//  (a) threads 0/1 of EVERY block derive wI/wJ into LDS (redundant, ~1 us,
//      concurrent across blocks) — removes the setup launch;
//  (b) round-5 per-thread-row streaming body (verified): 33x float2 row read,
//      LDS-broadcast weights, f64 W1/soc accumulation, wave+block reduce;
//  (c) last-block finalize via release-fence + device-scope atomic counter
//      (counter zeroed by a memset graph node each call) — removes the
//      finalize launch.
// ---------------------------------------------------------------------------
__global__ __launch_bounds__(256) void fused_kernel(
    const float* __restrict__ x, const float* __restrict__ soc,
    const float* __restrict__ W1,
    const float* __restrict__ ti, const float* __restrict__ tj,
    const float* __restrict__ b1, const float* __restrict__ W2,
    const float* __restrict__ b2,
    float* __restrict__ out, double* __restrict__ partials,
    unsigned int* __restrict__ counter)
{
    __shared__ __align__(16) float wi_s[KDIM];
    __shared__ __align__(16) float wj_s[KDIM];
    __shared__ double dp_s[2][KDIM];
    __shared__ double z_s[2][KDIM];
    __shared__ double red[4][12];
    __shared__ double red2[16][16];
    __shared__ double totals[12];
    __shared__ unsigned int is_last;

    const int tid = threadIdx.x;

    // ---- (a) per-block weight derivation (threads 0,1) ----
    if (tid < 2) {
        const float t = (tid == 0) ? ti[0] : tj[0];
        float* wo = (tid == 0) ? wi_s : wj_s;

        int kk = 0;
        float xkk = PRE.xk[0], xkk1 = PRE.xk[1];
#pragma unroll
        for (int k = 0; k <= KDIM - 2; ++k) {
            if (PRE.xk[k] <= t) { kk = k; xkk = PRE.xk[k]; xkk1 = PRE.xk[k + 1]; }
        }

        const double h  = (double)(xkk1 - xkk);
        const double u  = (double)(t - xkk);
        const double u2 = u * u, u3 = u2 * u, h2 = h * h;
        const double alpha = u3 / h2 - 2.0 * u2 / h + u;
        const double beta  = u3 / h2 - u2 / h;
        const double gamma = 3.0 * u2 / h - 2.0 * u3 / h2;

        double dpv = 0.0;
#pragma unroll
        for (int i = 0; i < KDIM; ++i) {
            double rhs = (i == kk) ? alpha : ((i == kk + 1) ? beta : 0.0);
            dpv = (rhs - PRE.av[i] * dpv) * PRE.winv[i];
            dp_s[tid][i] = dpv;
        }

        double zv = dp_s[tid][KDIM - 1];
        z_s[tid][KDIM - 1] = zv;
#pragma unroll
        for (int i = KDIM - 2; i >= 0; --i) {
            zv = dp_s[tid][i] - PRE.cp[i] * zv;
            z_s[tid][i] = zv;
        }

        const double z0  = z_s[tid][0];
        const double z65 = z_s[tid][KDIM - 1];
        double c = z0 * PRE.pp;
        double carryW = 0.0;
#pragma unroll
        for (int j = 1; j <= 64; ++j) {
            const double zj = z_s[tid][j];
            double full = c + zj * PRE.d3[j];
            if (j - 1 == kk) full += gamma;
            if (j == 64)     full += z65 * PRE.r1;
            const double w = full * PRE.dxinv[j - 1];
            double wy = carryW - w;
            if (j - 1 == kk) wy += 1.0;
            wo[j - 1] = (float)wy;
            carryW = w;
            c = zj * PRE.d3[j - 1];
            if (j == 1) c += z0 * PRE.qq;
        }
        double full64 = c + z65 * PRE.r2;
        if (kk == 64) full64 += gamma;
        const double w64 = full64 * PRE.dxinv[64];
        double wy64 = carryW - w64;
        if (kk == 64) wy64 += 1.0;
        wo[64] = (float)wy64;
        wo[65] = (float)w64;
    }
    __syncthreads();

    // ---- (b) streaming body (round-5 structure, verified) ----
    const int n = blockIdx.x * 256 + tid;

    float w1v[10];
#pragma unroll
    for (int o = 0; o < 10; ++o) w1v[o] = W1[(size_t)o * NROW + n];
    const float socv = soc[n];

    const float2* __restrict__ row = (const float2*)(x + (size_t)n * KDIM);
    const float2* wi2 = (const float2*)wi_s;
    const float2* wj2 = (const float2*)wj_s;
    float ri = 0.f, rj = 0.f;
#pragma unroll
    for (int k = 0; k < KDIM / 2; ++k) {
        const float2 v = row[k];
        const float2 a = wi2[k];
        const float2 b = wj2[k];
        ri = fmaf(v.x, a.x, ri); ri = fmaf(v.y, a.y, ri);
        rj = fmaf(v.x, b.x, rj); rj = fmaf(v.y, b.y, rj);
    }

    const float nd = (ri - rj) / (ri + rj);
    out[1 + n] = nd;                 // ndis slot of the output tuple

    const double ndd = (double)nd;
    double acc[12];
#pragma unroll
    for (int o = 0; o < 10; ++o) acc[o] = (double)w1v[o] * ndd;
    const double sv = (double)socv;
    acc[10] = sv;
    acc[11] = sv * sv;

#pragma unroll
    for (int o = 0; o < 12; ++o) {
        double v = acc[o];
#pragma unroll
        for (int off = 32; off > 0; off >>= 1) v += __shfl_down(v, off, 64);
        acc[o] = v;
    }
    const int wid  = tid >> 6;
    const int lane = tid & 63;
    if (lane == 0) {
#pragma unroll
        for (int o = 0; o < 12; ++o) red[wid][o] = acc[o];
    }
    __syncthreads();
    if (tid < 12) {
        double s = red[0][tid] + red[1][tid] + red[2][tid] + red[3][tid];
        partials[(size_t)blockIdx.x * PART_STRIDE + tid] = s;
    }

    // ---- (c) last-block finalize ----
    __threadfence();                 // release: partials visible device-wide
    __syncthreads();
    if (tid == 0) {
        unsigned int old = atomicAdd(counter, 1u);   // device-scope
        is_last = (old == NB - 1) ? 1u : 0u;
    }
    __syncthreads();
    if (is_last) {
        __threadfence();             // acquire: see all blocks' partials
        const int o = tid & 15, g = tid >> 4;        // 16 groups x 16 slots
        double s = 0.0;
        if (o < 12) {
            for (int b = g; b < NB; b += 16)
                s += partials[(size_t)b * PART_STRIDE + o];
        }
        red2[g][o] = s;
        __syncthreads();
        if (tid < 12) {
            double tot = 0.0;
            for (int g2 = 0; g2 < 16; ++g2) tot += red2[g2][tid];
            totals[tid] = tot;
        }
        __syncthreads();
        if (tid == 0) {
            double a2 = 0.0;
#pragma unroll
            for (int o2 = 0; o2 < 10; ++o2) {
                double h1 = totals[o2] + (double)b1[o2];
                h1 = (h1 > 0.0) ? h1 : 0.01 * h1;
                a2 += (double)W2[o2] * h1;
            }
            double shat = a2 + (double)b2[0];
            out[0] = (float)shat;
            double ssum = totals[10], ssum2 = totals[11];
            double loss = (double)NROW * shat * shat - 2.0 * shat * ssum + ssum2;
            out[1 + NROW] = (float)loss;
        }
    }
}

extern "C" void kernel_launch(void* const* d_in, const int* in_sizes, int n_in,
                              void* d_out, int out_size, void* d_ws, size_t ws_size,
                              hipStream_t stream) {
    const float* x   = (const float*)d_in[0];
    const float* soc = (const float*)d_in[1];
    const float* ti  = (const float*)d_in[2];
    const float* tj  = (const float*)d_in[3];
    const float* W1  = (const float*)d_in[4];
    const float* b1  = (const float*)d_in[5];
    const float* W2  = (const float*)d_in[6];
    const float* b2  = (const float*)d_in[7];
    float* out = (float*)d_out;

    double*       partials = (double*)d_ws;
    unsigned int* counter  = (unsigned int*)((char*)d_ws + CNT_OFF);

    hipMemsetAsync(counter, 0, sizeof(unsigned int), stream);
    fused_kernel<<<NB, 256, 0, stream>>>(x, soc, W1, ti, tj, b1, W2, b2,
                                         out, partials, counter);
}

// Round 7
// 279.342 us; speedup vs baseline: 2.2669x; 2.2669x over previous
//
#include <hip/hip_runtime.h>

#define NROW 524288
#define KDIM 66
#define NSEG 65
#define NB   2048
#define PART_STRIDE 12

// ws layout: [0, NB*12*8): double partials (10 h1 accs, sum_soc, sum_soc2)

// ---------------------------------------------------------------------------
// Compile-time precomputation of everything input-independent (round-4 fix:
// runtime version spilled ~5.3 KB/thread to scratch, 93.7 us).
// ---------------------------------------------------------------------------
struct Pre {
    float  xk[KDIM];
    float  dxf[NSEG];
    double av[KDIM];      // A^T lower diag
    double winv[KDIM];    // 1 / pivot
    double cp[KDIM];      // Thomas upper coeff
    double dxinv[NSEG];   // 1 / dx  (f64)
    double d3[NSEG];      // 3 * dx  (f64)
    double pp, qq, r1, r2;
};

constexpr Pre make_pre() {
    Pre p{};
    for (int k = 0; k < KDIM; ++k) p.xk[k] = (float)((1.0 / 65.0) * (double)k);
    p.xk[KDIM - 1] = 1.0f;
    for (int k = 0; k < NSEG; ++k) p.dxf[k] = p.xk[k + 1] - p.xk[k];

    double d02 = (double)(p.xk[2] - p.xk[0]);
    double dl  = (double)(p.xk[KDIM - 1] - p.xk[KDIM - 3]);

    double bv[KDIM] = {};
    double cv[KDIM] = {};
    bv[0] = (double)p.dxf[1];
    bv[KDIM - 1] = (double)p.dxf[KDIM - 3];
    for (int i = 1; i < KDIM - 1; ++i)
        bv[i] = 2.0 * ((double)p.dxf[i] + (double)p.dxf[i - 1]);
    p.av[0] = 0.0;
    p.av[1] = d02;
    for (int i = 2; i < KDIM; ++i) p.av[i] = (double)p.dxf[i - 2];
    for (int i = 0; i < KDIM - 2; ++i) cv[i] = (double)p.dxf[i + 1];
    cv[KDIM - 2] = dl;
    cv[KDIM - 1] = 0.0;

    double w = bv[0];
    p.winv[0] = 1.0 / w;
    p.cp[0]   = cv[0] / w;
    for (int i = 1; i < KDIM; ++i) {
        w = bv[i] - p.av[i] * p.cp[i - 1];
        p.winv[i] = 1.0 / w;
        p.cp[i]   = cv[i] / w;
    }
    for (int m = 0; m < NSEG; ++m) {
        p.dxinv[m] = 1.0 / (double)p.dxf[m];
        p.d3[m]    = 3.0 * (double)p.dxf[m];
    }
    p.pp = ((double)p.dxf[0] + 2.0 * d02) * (double)p.dxf[1] / d02;
    p.qq = (double)p.dxf[0] * (double)p.dxf[0] / d02;
    p.r1 = (double)p.dxf[64] * (double)p.dxf[64] / dl;
    p.r2 = (2.0 * dl + (double)p.dxf[64]) * (double)p.dxf[63] / dl;
    return p;
}

__device__ constexpr Pre PRE = make_pre();

// ---------------------------------------------------------------------------
// Main kernel = per-block weight derivation (threads 0/1, ~1-3 us, concurrent
// across the co-resident grid) + the verified round-5 streaming body.
// NO grid-wide fences/atomics — round 6 showed __threadfence() per wave costs
// ~8192 L2 writebacks (~440 us); a second launch is 100x cheaper.
// ---------------------------------------------------------------------------
__global__ __launch_bounds__(256) void main_kernel(
    const float* __restrict__ x, const float* __restrict__ soc,
    const float* __restrict__ W1,
    const float* __restrict__ ti, const float* __restrict__ tj,
    float* __restrict__ out_ndis, double* __restrict__ partials)
{
    __shared__ __align__(16) float wi_s[KDIM];
    __shared__ __align__(16) float wj_s[KDIM];
    __shared__ double dp_s[2][KDIM];
    __shared__ double z_s[2][KDIM];
    __shared__ double red[4][12];

    const int tid = threadIdx.x;

    // ---- per-block weight derivation (threads 0,1) ----
    if (tid < 2) {
        const float t = (tid == 0) ? ti[0] : tj[0];
        float* wo = (tid == 0) ? wi_s : wj_s;

        int kk = 0;
        float xkk = PRE.xk[0], xkk1 = PRE.xk[1];
#pragma unroll
        for (int k = 0; k <= KDIM - 2; ++k) {
            if (PRE.xk[k] <= t) { kk = k; xkk = PRE.xk[k]; xkk1 = PRE.xk[k + 1]; }
        }

        const double h  = (double)(xkk1 - xkk);
        const double u  = (double)(t - xkk);
        const double u2 = u * u, u3 = u2 * u, h2 = h * h;
        const double alpha = u3 / h2 - 2.0 * u2 / h + u;
        const double beta  = u3 / h2 - u2 / h;
        const double gamma = 3.0 * u2 / h - 2.0 * u3 / h2;

        double dpv = 0.0;
#pragma unroll
        for (int i = 0; i < KDIM; ++i) {
            double rhs = (i == kk) ? alpha : ((i == kk + 1) ? beta : 0.0);
            dpv = (rhs - PRE.av[i] * dpv) * PRE.winv[i];
            dp_s[tid][i] = dpv;
        }

        double zv = dp_s[tid][KDIM - 1];
        z_s[tid][KDIM - 1] = zv;
#pragma unroll
        for (int i = KDIM - 2; i >= 0; --i) {
            zv = dp_s[tid][i] - PRE.cp[i] * zv;
            z_s[tid][i] = zv;
        }

        const double z0  = z_s[tid][0];
        const double z65 = z_s[tid][KDIM - 1];
        double c = z0 * PRE.pp;
        double carryW = 0.0;
#pragma unroll
        for (int j = 1; j <= 64; ++j) {
            const double zj = z_s[tid][j];
            double full = c + zj * PRE.d3[j];
            if (j - 1 == kk) full += gamma;
            if (j == 64)     full += z65 * PRE.r1;
            const double w = full * PRE.dxinv[j - 1];
            double wy = carryW - w;
            if (j - 1 == kk) wy += 1.0;
            wo[j - 1] = (float)wy;
            carryW = w;
            c = zj * PRE.d3[j - 1];
            if (j == 1) c += z0 * PRE.qq;
        }
        double full64 = c + z65 * PRE.r2;
        if (kk == 64) full64 += gamma;
        const double w64 = full64 * PRE.dxinv[64];
        double wy64 = carryW - w64;
        if (kk == 64) wy64 += 1.0;
        wo[64] = (float)wy64;
        wo[65] = (float)w64;
    }
    __syncthreads();

    // ---- streaming body (round-5 structure, verified fast) ----
    const int n = blockIdx.x * 256 + tid;

    float w1v[10];
#pragma unroll
    for (int o = 0; o < 10; ++o) w1v[o] = W1[(size_t)o * NROW + n];
    const float socv = soc[n];

    const float2* __restrict__ row = (const float2*)(x + (size_t)n * KDIM);
    const float2* wi2 = (const float2*)wi_s;
    const float2* wj2 = (const float2*)wj_s;
    float ri = 0.f, rj = 0.f;
#pragma unroll
    for (int k = 0; k < KDIM / 2; ++k) {
        const float2 v = row[k];
        const float2 a = wi2[k];
        const float2 b = wj2[k];
        ri = fmaf(v.x, a.x, ri); ri = fmaf(v.y, a.y, ri);
        rj = fmaf(v.x, b.x, rj); rj = fmaf(v.y, b.y, rj);
    }

    const float nd = (ri - rj) / (ri + rj);
    out_ndis[n] = nd;

    const double ndd = (double)nd;
    double acc[12];
#pragma unroll
    for (int o = 0; o < 10; ++o) acc[o] = (double)w1v[o] * ndd;
    const double sv = (double)socv;
    acc[10] = sv;
    acc[11] = sv * sv;

#pragma unroll
    for (int o = 0; o < 12; ++o) {
        double v = acc[o];
#pragma unroll
        for (int off = 32; off > 0; off >>= 1) v += __shfl_down(v, off, 64);
        acc[o] = v;
    }
    const int wid  = tid >> 6;
    const int lane = tid & 63;
    if (lane == 0) {
#pragma unroll
        for (int o = 0; o < 12; ++o) red[wid][o] = acc[o];
    }
    __syncthreads();
    if (tid < 12) {
        double s = red[0][tid] + red[1][tid] + red[2][tid] + red[3][tid];
        partials[(size_t)blockIdx.x * PART_STRIDE + tid] = s;
    }
}

// ---------------------------------------------------------------------------
// Finalize (own launch — implicit inter-kernel ordering replaces fences):
// reduce 2048x12 partials, b1 / leaky-relu / W2 / b2, closed-form loss
// N*s^2 - 2*s*sum(soc) + sum(soc^2).
// ---------------------------------------------------------------------------
__global__ void finalize_kernel(const double* __restrict__ partials,
                                const float* __restrict__ b1,
                                const float* __restrict__ W2,
                                const float* __restrict__ b2,
                                float* __restrict__ out)
{
    __shared__ double red[16][16];
    __shared__ double totals[12];
    int tid = threadIdx.x;
    int o = tid & 15, g = tid >> 4;     // 16 groups x 16 slots (12 used)
    double s = 0.0;
    if (o < 12) {
        for (int b = g; b < NB; b += 16)
            s += partials[(size_t)b * PART_STRIDE + o];
    }
    red[g][o] = s;
    __syncthreads();
    if (tid < 12) {
        double tot = 0.0;
        for (int g2 = 0; g2 < 16; ++g2) tot += red[g2][tid];
        totals[tid] = tot;
    }
    __syncthreads();
    if (tid == 0) {
        double acc = 0.0;
#pragma unroll
        for (int o2 = 0; o2 < 10; ++o2) {
            double h1 = totals[o2] + (double)b1[o2];
            h1 = (h1 > 0.0) ? h1 : 0.01 * h1;
            acc += (double)W2[o2] * h1;
        }
        double shat = acc + (double)b2[0];
        out[0] = (float)shat;
        double ssum = totals[10], ssum2 = totals[11];
        double loss = (double)NROW * shat * shat - 2.0 * shat * ssum + ssum2;
        out[1 + NROW] = (float)loss;
    }
}

extern "C" void kernel_launch(void* const* d_in, const int* in_sizes, int n_in,
                              void* d_out, int out_size, void* d_ws, size_t ws_size,
                              hipStream_t stream) {
    const float* x   = (const float*)d_in[0];
    const float* soc = (const float*)d_in[1];
    const float* ti  = (const float*)d_in[2];
    const float* tj  = (const float*)d_in[3];
    const float* W1  = (const float*)d_in[4];
    const float* b1  = (const float*)d_in[5];
    const float* W2  = (const float*)d_in[6];
    const float* b2  = (const float*)d_in[7];
    float* out = (float*)d_out;

    double* partials = (double*)d_ws;

    main_kernel<<<NB, 256, 0, stream>>>(x, soc, W1, ti, tj, out + 1, partials);
    finalize_kernel<<<1, 256, 0, stream>>>(partials, b1, W2, b2, out);
}